// Round 4
// baseline (111.768 us; speedup 1.0000x reference)
//
#include <hip/hip_runtime.h>

// Correlation layer (FlowNet-style), max_displacement=4.
// in1,in2: [8,256,128,128] fp32 -> out: [8,81,128,128] fp32
// out[b, dy*9+dx, y, x] = sum_c in1[b,c,y,x] * in2[b,c,y+dy-4,x+dx-4] (0 if OOB)
//
// Round-4: double-buffered LDS pipeline (issue-early / write-late staging),
// hoisted per-thread staging descriptors, f16x2 + v_dot2_f32_f16 compute.

constexpr int Bn = 8, Cn = 256, Hn = 128, Wn = 128, HW = Hn * Wn;
constexpr int Dd = 4, ND = 9;
constexpr int KC = 8, NP = KC / 2;     // 4 f16x2 channel-pairs per chunk
constexpr int NCH = Cn / KC;           // 32 chunks
constexpr int NT = 576;                // 9 waves: dy(9) x (2 rows x 32 quads)
constexpr int W2 = Wn + 8;             // padded in2 row width (136 u32)
constexpr int S1SZ = NP * 2 * Wn;      // 1024 u32
constexpr int S2SZ = NP * 10 * W2;     // 5440 u32
constexpr int BUF  = S1SZ + S2SZ;      // 6464 u32 -> 2 buffers = 51.7 KB
constexpr int KCHW = KC * HW;

typedef __fp16 h2v __attribute__((ext_vector_type(2)));

static __device__ __forceinline__ unsigned packh2(float a, float b) {
  h2v h = __builtin_amdgcn_cvt_pkrtz(a, b);   // a->low, b->high
  return __builtin_bit_cast(unsigned, h);
}

static __device__ __forceinline__ float dot2(unsigned a, unsigned b, float c) {
#if __has_builtin(__builtin_amdgcn_fdot2)
  return __builtin_amdgcn_fdot2(__builtin_bit_cast(h2v, a),
                                __builtin_bit_cast(h2v, b), c, false);
#else
  h2v ha = __builtin_bit_cast(h2v, a), hb = __builtin_bit_cast(h2v, b);
  return c + (float)ha.x * (float)hb.x + (float)ha.y * (float)hb.y;
#endif
}

__global__ __launch_bounds__(NT) void corr_kernel(
    const float* __restrict__ in1, const float* __restrict__ in2,
    float* __restrict__ out)
{
  __shared__ __align__(16) unsigned lds[2 * BUF];

  // XCD-chunked swizzle: 512 blocks, 8 XCDs, bijective (512 % 8 == 0).
  int bid = blockIdx.x;
  bid = (bid & 7) * 64 + (bid >> 3);
  const int b  = bid >> 6;
  const int y0 = (bid & 63) << 1;

  const int tid  = threadIdx.x;
  const int dy   = tid >> 6;           // 0..8 (wave id)
  const int lane = tid & 63;
  const int row  = lane >> 5;          // 0..1
  const int xq   = (lane & 31) << 2;   // 4 consecutive px
  const int srow = dy + row;
  const size_t base = (size_t)b * Cn * HW;

  // ---- per-thread staging descriptors: 3 fixed float4-groups, hoisted ----
  // groups: [0,256) in1 (NP*2rows*32quads), [256,1536) in2 (NP*10rows*32quads)
  const bool stager = tid < 512;
  const float* src[3]; int dst[3]; bool ok[3];
#pragma unroll
  for (int s = 0; s < 3; ++s) {
    const int g = (tid & 511) + s * 512;
    if (g < 256) {
      const int p = g >> 6, yy = (g >> 5) & 1, gx = (g & 31) << 2;
      src[s] = in1 + base + (size_t)(2 * p) * HW + (y0 + yy) * Wn + gx;
      dst[s] = p * (2 * Wn) + yy * Wn + gx;
      ok[s]  = true;
    } else {
      const int g2 = g - 256;
      const int p = g2 / 320, rem = g2 - p * 320;
      const int r = rem >> 5, gx = (rem & 31) << 2;
      const int gy = y0 + r - Dd;
      ok[s] = (unsigned)gy < (unsigned)Hn;
      src[s] = in2 + base + (size_t)(2 * p) * HW + (size_t)(ok[s] ? gy : 0) * Wn + gx;
      dst[s] = S1SZ + (p * 10 + r) * W2 + 4 + gx;
    }
  }

  // ---- zero halo cols [0..3],[132..135] of both buffers (written only here,
  //      disjoint from staged interior -> no extra barrier needed) ----
  for (int i = tid; i < 2 * NP * 10 * 2; i += NT) {
    const int bh = i / (NP * 10 * 2), rem = i - bh * (NP * 10 * 2);
    const int pr = rem >> 1, side = rem & 1;
    *(uint4*)&lds[bh * BUF + S1SZ + pr * W2 + side * 132] = uint4{0, 0, 0, 0};
  }

  // ---- prefetch + commit chunk 0 into buffer 0 ----
  float4 pre[3][2];
  if (stager) {
#pragma unroll
    for (int s = 0; s < 3; ++s) {
      pre[s][0] = *(const float4*)src[s];
      pre[s][1] = *(const float4*)(src[s] + HW);
    }
#pragma unroll
    for (int s = 0; s < 3; ++s) {
      uint4 w;
      w.x = packh2(pre[s][0].x, pre[s][1].x); w.y = packh2(pre[s][0].y, pre[s][1].y);
      w.z = packh2(pre[s][0].z, pre[s][1].z); w.w = packh2(pre[s][0].w, pre[s][1].w);
      if (!ok[s]) w = uint4{0, 0, 0, 0};
      *(uint4*)&lds[dst[s]] = w;
    }
  }
  __syncthreads();

  float4 acc[ND];
#pragma unroll
  for (int dx = 0; dx < ND; ++dx) acc[dx] = float4{0.f, 0.f, 0.f, 0.f};

  for (int c = 0; c < NCH; ++c) {
    const int  cur  = c & 1;
    const bool more = (c + 1) < NCH;

    // issue next chunk's global loads early (in flight across compute)
    if (more && stager) {
      const size_t ofs = (size_t)(c + 1) * KCHW;
#pragma unroll
      for (int s = 0; s < 3; ++s) {
        pre[s][0] = *(const float4*)(src[s] + ofs);
        pre[s][1] = *(const float4*)(src[s] + ofs + HW);
      }
    }

    // compute current buffer: per pair 4x ds_read_b128 -> 36 dot2
    const unsigned* bufp = &lds[cur * BUF];
#pragma unroll
    for (int kc = 0; kc < NP; ++kc) {
      const uint4 av = *(const uint4*)(bufp + kc * (2 * Wn) + row * Wn + xq);
      const unsigned* bp = bufp + S1SZ + (kc * 10 + srow) * W2 + xq;
      const uint4 b0 = *(const uint4*)bp;
      const uint4 b1 = *(const uint4*)(bp + 4);
      const uint4 b2 = *(const uint4*)(bp + 8);
      const unsigned aa[4]  = {av.x, av.y, av.z, av.w};
      const unsigned bb[12] = {b0.x, b0.y, b0.z, b0.w, b1.x, b1.y,
                               b1.z, b1.w, b2.x, b2.y, b2.z, b2.w};
#pragma unroll
      for (int dx = 0; dx < ND; ++dx) {
        acc[dx].x = dot2(aa[0], bb[dx + 0], acc[dx].x);
        acc[dx].y = dot2(aa[1], bb[dx + 1], acc[dx].y);
        acc[dx].z = dot2(aa[2], bb[dx + 2], acc[dx].z);
        acc[dx].w = dot2(aa[3], bb[dx + 3], acc[dx].w);
      }
    }

    // pack + write next chunk into the other buffer
    if (more && stager) {
      const int nb = (cur ^ 1) * BUF;
#pragma unroll
      for (int s = 0; s < 3; ++s) {
        uint4 w;
        w.x = packh2(pre[s][0].x, pre[s][1].x); w.y = packh2(pre[s][0].y, pre[s][1].y);
        w.z = packh2(pre[s][0].z, pre[s][1].z); w.w = packh2(pre[s][0].w, pre[s][1].w);
        if (!ok[s]) w = uint4{0, 0, 0, 0};
        *(uint4*)&lds[nb + dst[s]] = w;
      }
    }
    __syncthreads();
  }

  // ---- epilogue: coalesced float4 stores ----
#pragma unroll
  for (int dx = 0; dx < ND; ++dx) {
    const size_t o =
        (((size_t)b * (ND * ND) + dy * ND + dx) * Hn + (y0 + row)) * Wn + xq;
    *(float4*)&out[o] = acc[dx];
  }
}

extern "C" void kernel_launch(void* const* d_in, const int* in_sizes, int n_in,
                              void* d_out, int out_size, void* d_ws, size_t ws_size,
                              hipStream_t stream) {
  const float* in1 = (const float*)d_in[0];
  const float* in2 = (const float*)d_in[1];
  float* out = (float*)d_out;
  dim3 grid(Bn * (Hn / 2));   // 512 blocks: (batch, y-pair)
  dim3 block(NT);             // 576 threads = 9 waves
  hipLaunchKernelGGL(corr_kernel, grid, block, 0, stream, in1, in2, out);
}